// Round 2
// baseline (712.205 us; speedup 1.0000x reference)
//
#include <hip/hip_runtime.h>
#include <hip/hip_bf16.h>
#include <math.h>

typedef __attribute__((ext_vector_type(8))) short bh8;
typedef __attribute__((ext_vector_type(4))) float fx4;

__device__ __forceinline__ fx4 mfma_bf16(bh8 a, bh8 b, fx4 c) {
    return __builtin_amdgcn_mfma_f32_16x16x32_bf16(a, b, c, 0, 0, 0);
}

// ---------------- weight convert+transpose: W[K][N] fp32 -> Wt[N][K] bf16 ----------------
__global__ __launch_bounds__(256)
void convw_k(const float* __restrict__ W, __hip_bfloat16* __restrict__ Wt, int K, int Nn)
{
    int idx = blockIdx.x * 256 + threadIdx.x;
    if (idx < K * Nn) {
        int k = idx / Nn, n = idx - k * Nn;
        Wt[(size_t)n * K + k] = __float2bfloat16(W[idx]);
    }
}

// ---------------- LN1 + shift + window-partition gather -> xw bf16 (window order) -------
__global__ __launch_bounds__(256)
void ln1_gather_k(const float* __restrict__ x, const float* __restrict__ g,
                  const float* __restrict__ bia, __hip_bfloat16* __restrict__ xw)
{
    const int wave = threadIdx.x >> 6, lane = threadIdx.x & 63;
    const int t = blockIdx.x * 4 + wave;        // window-ordered token, < 100352
    const int w = t / 49, n = t - w * 49;
    const int b = w >> 6, wrem = w & 63, wi = wrem >> 3, wj = wrem & 7;
    const int i = n / 7, j = n - i * 7;
    int sr = wi * 7 + i + 3; if (sr >= 56) sr -= 56;
    int sc = wj * 7 + j + 3; if (sc >= 56) sc -= 56;
    const float* xp = x + ((size_t)b * 3136 + sr * 56 + sc) * 192;
    float v0 = xp[lane], v1 = xp[lane + 64], v2 = xp[lane + 128];
    float s = v0 + v1 + v2;
    float q = v0 * v0 + v1 * v1 + v2 * v2;
    for (int off = 32; off > 0; off >>= 1) {
        s += __shfl_down(s, off, 64);
        q += __shfl_down(q, off, 64);
    }
    s = __shfl(s, 0, 64); q = __shfl(q, 0, 64);
    float mean = s * (1.0f / 192.0f);
    float var  = q * (1.0f / 192.0f) - mean * mean;
    float rstd = rsqrtf(var + 1e-5f);
    __hip_bfloat16* op = xw + (size_t)t * 192;
    op[lane]       = __float2bfloat16((v0 - mean) * rstd * g[lane]       + bia[lane]);
    op[lane + 64]  = __float2bfloat16((v1 - mean) * rstd * g[lane + 64]  + bia[lane + 64]);
    op[lane + 128] = __float2bfloat16((v2 - mean) * rstd * g[lane + 128] + bia[lane + 128]);
}

// ---------------- LN2 (no gather): x1 fp32 -> y2 bf16 ----------------
__global__ __launch_bounds__(256)
void ln2_k(const float* __restrict__ xin, const float* __restrict__ g,
           const float* __restrict__ bia, __hip_bfloat16* __restrict__ out)
{
    const int wave = threadIdx.x >> 6, lane = threadIdx.x & 63;
    const int t = blockIdx.x * 4 + wave;
    const float* xp = xin + (size_t)t * 192;
    float v0 = xp[lane], v1 = xp[lane + 64], v2 = xp[lane + 128];
    float s = v0 + v1 + v2;
    float q = v0 * v0 + v1 * v1 + v2 * v2;
    for (int off = 32; off > 0; off >>= 1) {
        s += __shfl_down(s, off, 64);
        q += __shfl_down(q, off, 64);
    }
    s = __shfl(s, 0, 64); q = __shfl(q, 0, 64);
    float mean = s * (1.0f / 192.0f);
    float var  = q * (1.0f / 192.0f) - mean * mean;
    float rstd = rsqrtf(var + 1e-5f);
    __hip_bfloat16* op = out + (size_t)t * 192;
    op[lane]       = __float2bfloat16((v0 - mean) * rstd * g[lane]       + bia[lane]);
    op[lane + 64]  = __float2bfloat16((v1 - mean) * rstd * g[lane + 64]  + bia[lane + 64]);
    op[lane + 128] = __float2bfloat16((v2 - mean) * rstd * g[lane + 128] + bia[lane + 128]);
}

// ---------------- generic bf16 GEMM: C[M][NOUT] = A[M][K] * Bt[NOUT][K]^T + epilogue ----
// MODE 0: qkv  (+bias, scale first 192 cols, out bf16)
// MODE 1: proj (+bias +resid fp32, out fp32)
// MODE 2: fc1  (+bias, exact gelu, out bf16)
// MODE 3: fc2  (+bias +resid fp32, out fp32)
template<int MODE, int K, int NOUT>
__global__ __launch_bounds__(256)
void gemm_k(const __hip_bfloat16* __restrict__ A,
            const __hip_bfloat16* __restrict__ Bt,
            const float* __restrict__ bias,
            const float* __restrict__ resid,
            void* __restrict__ outv)
{
    __shared__ __align__(16) __hip_bfloat16 As[64 * 32];
    __shared__ __align__(16) __hip_bfloat16 Bs[64 * 32];
    const int tid  = threadIdx.x;
    const int lane = tid & 63, wave = tid >> 6;
    const int quad = lane >> 4, l15 = lane & 15;
    const int wr = wave >> 1, wc = wave & 1;
    const int m0 = blockIdx.x * 64, n0 = blockIdx.y * 64;
    const int srow = tid >> 2, sch = (tid & 3) * 8;
    const __hip_bfloat16* Ap = A  + (size_t)(m0 + srow) * K + sch;
    const __hip_bfloat16* Bp = Bt + (size_t)(n0 + srow) * K + sch;

    fx4 acc[2][2];
    acc[0][0] = {0.f, 0.f, 0.f, 0.f}; acc[0][1] = {0.f, 0.f, 0.f, 0.f};
    acc[1][0] = {0.f, 0.f, 0.f, 0.f}; acc[1][1] = {0.f, 0.f, 0.f, 0.f};

    for (int k0 = 0; k0 < K; k0 += 32) {
        *(bh8*)&As[srow * 32 + sch] = *(const bh8*)(Ap + k0);
        *(bh8*)&Bs[srow * 32 + sch] = *(const bh8*)(Bp + k0);
        __syncthreads();
        bh8 a0 = *(const bh8*)&As[(wr * 32 + l15)      * 32 + quad * 8];
        bh8 a1 = *(const bh8*)&As[(wr * 32 + 16 + l15) * 32 + quad * 8];
        bh8 b0 = *(const bh8*)&Bs[(wc * 32 + l15)      * 32 + quad * 8];
        bh8 b1 = *(const bh8*)&Bs[(wc * 32 + 16 + l15) * 32 + quad * 8];
        acc[0][0] = mfma_bf16(a0, b0, acc[0][0]);
        acc[0][1] = mfma_bf16(a0, b1, acc[0][1]);
        acc[1][0] = mfma_bf16(a1, b0, acc[1][0]);
        acc[1][1] = mfma_bf16(a1, b1, acc[1][1]);
        __syncthreads();
    }

#pragma unroll
    for (int mi = 0; mi < 2; mi++)
#pragma unroll
    for (int ni = 0; ni < 2; ni++) {
        const int n = n0 + wc * 32 + ni * 16 + l15;
        const float bn = bias[n];
#pragma unroll
        for (int r = 0; r < 4; r++) {
            const int m = m0 + wr * 32 + mi * 16 + quad * 4 + r;
            float v = acc[mi][ni][r] + bn;
            if (MODE == 0) {
                if (n < 192) v *= 0.17677669529663687f;   // SCALE = 32^-0.5 on q
                ((__hip_bfloat16*)outv)[(size_t)m * NOUT + n] = __float2bfloat16(v);
            } else if (MODE == 1) {
                ((float*)outv)[(size_t)m * NOUT + n] = v + resid[(size_t)m * NOUT + n];
            } else if (MODE == 2) {
                v = 0.5f * v * (1.0f + erff(v * 0.70710678118654752f));
                ((__hip_bfloat16*)outv)[(size_t)m * NOUT + n] = __float2bfloat16(v);
            } else {
                ((float*)outv)[(size_t)m * NOUT + n] = v + resid[(size_t)m * NOUT + n];
            }
        }
    }
}

// ---------------- attention: one block per (window, head), chunked over windows ---------
__global__ __launch_bounds__(256)
void attn_k(const __hip_bfloat16* __restrict__ qkv,   // chunk-local: [WCH][49][576]
            const float* __restrict__ bias_table,
            __hip_bfloat16* __restrict__ aout,        // full buffer, orig token order
            int w_offset)
{
    __shared__ __align__(16) __hip_bfloat16 Qb[64 * 32];
    __shared__ __align__(16) __hip_bfloat16 Kb[64 * 32];
    __shared__ __align__(16) __hip_bfloat16 Vt[32 * 64];   // Vt[d][m]
    __shared__ __align__(16) __hip_bfloat16 Ps[64 * 72];   // padded stride 72
    __shared__ float bias_h[169];

    const int tid  = threadIdx.x;
    const int lane = tid & 63, wave = tid >> 6;
    const int quad = lane >> 4, l15 = lane & 15;
    const int wl = blockIdx.x / 6, hd = blockIdx.x % 6;    // wl = chunk-local window
    const int w = w_offset + wl;                           // global window id
    const int b = w >> 6, wrem = w & 63, wi = wrem >> 3, wj = wrem & 7;
    const size_t base = (size_t)wl * 49 * 576 + hd * 32;

    if (tid < 169) bias_h[tid] = bias_table[tid * 6 + hd];

    bh8 z = {0, 0, 0, 0, 0, 0, 0, 0};
    {
        int row = tid >> 2, ch = (tid & 3) * 8;
        if (row < 49) {
            *(bh8*)&Qb[row * 32 + ch] = *(const bh8*)(qkv + base + (size_t)row * 576 + ch);
            *(bh8*)&Kb[row * 32 + ch] = *(const bh8*)(qkv + base + (size_t)row * 576 + 192 + ch);
        } else {
            *(bh8*)&Qb[row * 32 + ch] = z;
            *(bh8*)&Kb[row * 32 + ch] = z;
        }
        *(bh8*)&Vt[tid * 8] = z;    // zero all of Vt
    }
    __syncthreads();
    for (int idx = tid; idx < 49 * 32; idx += 256) {       // V transpose scatter
        int n = idx >> 5, d = idx & 31;
        Vt[d * 64 + n] = qkv[base + (size_t)n * 576 + 384 + d];
    }
    __syncthreads();

    // ---- scores S = Q K^T : wave handles rows [wave*16, wave*16+16) x all 64 cols ----
    fx4 zf = {0.f, 0.f, 0.f, 0.f};
    bh8 aq = *(const bh8*)&Qb[(wave * 16 + l15) * 32 + quad * 8];
    fx4 sarr[4];
#pragma unroll
    for (int ni = 0; ni < 4; ni++) {
        bh8 bk = *(const bh8*)&Kb[(ni * 16 + l15) * 32 + quad * 8];
        sarr[ni] = mfma_bf16(aq, bk, zf);
    }

    // ---- bias + mask + softmax (rows live on lanes sharing the same quad) ----
    int iarr[4], ria[4], cia[4], mbi[4];
#pragma unroll
    for (int r = 0; r < 4; r++) {
        int i = wave * 16 + quad * 4 + r;
        int ri = i / 7, ci = i - ri * 7;
        iarr[r] = i; ria[r] = ri; cia[r] = ci;
        int ar = wi * 7 + ri, ac = wj * 7 + ci;
        int br = (ar < 49) ? 0 : ((ar < 53) ? 1 : 2);
        int bc = (ac < 49) ? 0 : ((ac < 53) ? 1 : 2);
        mbi[r] = br * 3 + bc;
    }
    float vals[4][4];   // [ni][r]
#pragma unroll
    for (int ni = 0; ni < 4; ni++) {
        int jcol = ni * 16 + l15;
        int rj = jcol / 7, cj = jcol - rj * 7;
        int ar = wi * 7 + rj, ac = wj * 7 + cj;
        int br = (ar < 49) ? 0 : ((ar < 53) ? 1 : 2);
        int bc = (ac < 49) ? 0 : ((ac < 53) ? 1 : 2);
        int mbj = br * 3 + bc;
#pragma unroll
        for (int r = 0; r < 4; r++) {
            float v;
            if (jcol >= 49)            v = -1e30f;
            else if (iarr[r] >= 49)    v = 0.0f;
            else {
                int bidx = (ria[r] - rj + 6) * 13 + (cia[r] - cj + 6);
                v = sarr[ni][r] + bias_h[bidx] + ((mbi[r] != mbj) ? -100.0f : 0.0f);
            }
            vals[ni][r] = v;
        }
    }
#pragma unroll
    for (int r = 0; r < 4; r++) {
        float mx = fmaxf(fmaxf(vals[0][r], vals[1][r]), fmaxf(vals[2][r], vals[3][r]));
        mx = fmaxf(mx, __shfl_xor(mx, 1, 64));
        mx = fmaxf(mx, __shfl_xor(mx, 2, 64));
        mx = fmaxf(mx, __shfl_xor(mx, 4, 64));
        mx = fmaxf(mx, __shfl_xor(mx, 8, 64));
        float e0 = __expf(vals[0][r] - mx);
        float e1 = __expf(vals[1][r] - mx);
        float e2 = __expf(vals[2][r] - mx);
        float e3 = __expf(vals[3][r] - mx);
        float sm = e0 + e1 + e2 + e3;
        sm += __shfl_xor(sm, 1, 64);
        sm += __shfl_xor(sm, 2, 64);
        sm += __shfl_xor(sm, 4, 64);
        sm += __shfl_xor(sm, 8, 64);
        float inv = 1.0f / sm;
        int prow = (wave * 16 + quad * 4 + r) * 72;
        Ps[prow + 0 * 16 + l15] = __float2bfloat16(e0 * inv);
        Ps[prow + 1 * 16 + l15] = __float2bfloat16(e1 * inv);
        Ps[prow + 2 * 16 + l15] = __float2bfloat16(e2 * inv);
        Ps[prow + 3 * 16 + l15] = __float2bfloat16(e3 * inv);
    }
    __syncthreads();

    // ---- O = P V : wave's 16 rows x 32 dims ----
    fx4 o0 = zf, o1 = zf;
#pragma unroll
    for (int k0 = 0; k0 < 64; k0 += 32) {
        bh8 ap  = *(const bh8*)&Ps[(wave * 16 + l15) * 72 + k0 + quad * 8];
        bh8 bv0 = *(const bh8*)&Vt[(l15)      * 64 + k0 + quad * 8];
        bh8 bv1 = *(const bh8*)&Vt[(16 + l15) * 64 + k0 + quad * 8];
        o0 = mfma_bf16(ap, bv0, o0);
        o1 = mfma_bf16(ap, bv1, o1);
    }

    // ---- write out in ORIGINAL token order (reverse window + reverse roll) ----
#pragma unroll
    for (int r = 0; r < 4; r++) {
        int m = wave * 16 + quad * 4 + r;
        if (m < 49) {
            int i = m / 7, j2 = m - i * 7;
            int orow = wi * 7 + i + 3;  if (orow >= 56) orow -= 56;
            int ocol = wj * 7 + j2 + 3; if (ocol >= 56) ocol -= 56;
            size_t t = (size_t)b * 3136 + orow * 56 + ocol;
            aout[t * 192 + hd * 32 + l15]      = __float2bfloat16(o0[r]);
            aout[t * 192 + hd * 32 + 16 + l15] = __float2bfloat16(o1[r]);
        }
    }
}

// ---------------- launch ----------------
// Scratch plan (peak 58.7 MB; previous 309 MB version crashed -> suspected ws overrun):
//   buf1 @ 0         (38,535,168 B): xw (window order) -> aliased attn_out (orig order,
//                     chunk c of attn only overwrites the 1/8 already consumed by QKV
//                     gemm chunk c) -> y2 (LN2 out)
//   buf2 @ 38535168  (19,267,584 B): qkv chunk (14.45 MB) / hbuf chunk (19.27 MB)
//   weights @ 57802752 .. 58687488
//   x1 lives in d_out (fp32); FC2 does in-place owner-computes resid add on d_out.
extern "C" void kernel_launch(void* const* d_in, const int* in_sizes, int n_in,
                              void* d_out, int out_size, void* d_ws, size_t ws_size,
                              hipStream_t stream)
{
    const float* x      = (const float*)d_in[0];
    const float* n1g    = (const float*)d_in[1];
    const float* n1b    = (const float*)d_in[2];
    const float* qkv_w  = (const float*)d_in[3];
    const float* qkv_b  = (const float*)d_in[4];
    const float* proj_w = (const float*)d_in[5];
    const float* proj_b = (const float*)d_in[6];
    const float* btab   = (const float*)d_in[7];
    const float* n2g    = (const float*)d_in[8];
    const float* n2b    = (const float*)d_in[9];
    const float* fc1_w  = (const float*)d_in[10];
    const float* fc1_b  = (const float*)d_in[11];
    const float* fc2_w  = (const float*)d_in[12];
    const float* fc2_b  = (const float*)d_in[13];

    char* ws = (char*)d_ws;
    __hip_bfloat16* buf1    = (__hip_bfloat16*)(ws + 0);          // 38,535,168 B
    __hip_bfloat16* buf2    = (__hip_bfloat16*)(ws + 38535168);   // 19,267,584 B
    __hip_bfloat16* wt_qkv  = (__hip_bfloat16*)(ws + 57802752);   // 221,184 B
    __hip_bfloat16* wt_proj = (__hip_bfloat16*)(ws + 58023936);   // 73,728 B
    __hip_bfloat16* wt_fc1  = (__hip_bfloat16*)(ws + 58097664);   // 294,912 B
    __hip_bfloat16* wt_fc2  = (__hip_bfloat16*)(ws + 58392576);   // 294,912 B
    float*          x1      = (float*)d_out;                      // 77,070,336 B

    convw_k<<<dim3(432), 256, 0, stream>>>(qkv_w, wt_qkv, 192, 576);
    convw_k<<<dim3(144), 256, 0, stream>>>(proj_w, wt_proj, 192, 192);
    convw_k<<<dim3(576), 256, 0, stream>>>(fc1_w, wt_fc1, 192, 768);
    convw_k<<<dim3(576), 256, 0, stream>>>(fc2_w, wt_fc2, 768, 192);

    // LN1 + shift + window partition: 100352 tokens
    ln1_gather_k<<<dim3(25088), 256, 0, stream>>>(x, n1g, n1b, buf1);

    // QKV gemm + attention, 8 chunks of 256 windows (12544 rows)
    const int WCH = 256, RCH = WCH * 49;   // 12544
    for (int c = 0; c < 8; c++) {
        gemm_k<0, 192, 576><<<dim3(RCH / 64, 9), 256, 0, stream>>>(
            buf1 + (size_t)c * RCH * 192, wt_qkv, qkv_b, nullptr, buf2);
        attn_k<<<dim3(WCH * 6), 256, 0, stream>>>(buf2, btab, buf1, c * WCH);
    }

    // proj + residual -> x1 (in d_out)
    gemm_k<1, 192, 192><<<dim3(1568, 3), 256, 0, stream>>>(buf1, wt_proj, proj_b, x, x1);

    // LN2 -> y2 (buf1)
    ln2_k<<<dim3(25088), 256, 0, stream>>>(x1, n2g, n2b, buf1);

    // MLP, 8 chunks of 12544 rows; hbuf = buf2; FC2 residual in-place on d_out
    for (int c = 0; c < 8; c++) {
        gemm_k<2, 192, 768><<<dim3(RCH / 64, 12), 256, 0, stream>>>(
            buf1 + (size_t)c * RCH * 192, wt_fc1, fc1_b, nullptr, buf2);
        gemm_k<3, 768, 192><<<dim3(RCH / 64, 3), 256, 0, stream>>>(
            buf2, wt_fc2, fc2_b, x1 + (size_t)c * RCH * 192, x1 + (size_t)c * RCH * 192);
    }
}

// Round 3
// 553.375 us; speedup vs baseline: 1.2870x; 1.2870x over previous
//
#include <hip/hip_runtime.h>
#include <hip/hip_bf16.h>
#include <math.h>

typedef __attribute__((ext_vector_type(8))) short bh8;
typedef __attribute__((ext_vector_type(4))) float fx4;

__device__ __forceinline__ fx4 mfma_bf16(bh8 a, bh8 b, fx4 c) {
    return __builtin_amdgcn_mfma_f32_16x16x32_bf16(a, b, c, 0, 0, 0);
}

// async global->LDS, 16B per lane. LDS dest = wave-uniform base + lane*16.
__device__ __forceinline__ void gload16(const __hip_bfloat16* g, __hip_bfloat16* l) {
    __builtin_amdgcn_global_load_lds(
        (const __attribute__((address_space(1))) void*)g,
        (__attribute__((address_space(3))) void*)l,
        16, 0, 0);
}

// ---------------- weight convert+transpose: W[K][N] fp32 -> Wt[N][K] bf16 ----------------
__global__ __launch_bounds__(256)
void convw_k(const float* __restrict__ W, __hip_bfloat16* __restrict__ Wt, int K, int Nn)
{
    int idx = blockIdx.x * 256 + threadIdx.x;
    if (idx < K * Nn) {
        int k = idx / Nn, n = idx - k * Nn;
        Wt[(size_t)n * K + k] = __float2bfloat16(W[idx]);
    }
}

// ---------------- LN1 + shift + window-partition gather -> xw bf16 (window order) -------
__global__ __launch_bounds__(256)
void ln1_gather_k(const float* __restrict__ x, const float* __restrict__ g,
                  const float* __restrict__ bia, __hip_bfloat16* __restrict__ xw)
{
    const int wave = threadIdx.x >> 6, lane = threadIdx.x & 63;
    const int t = blockIdx.x * 4 + wave;        // window-ordered token, < 100352
    const int w = t / 49, n = t - w * 49;
    const int b = w >> 6, wrem = w & 63, wi = wrem >> 3, wj = wrem & 7;
    const int i = n / 7, j = n - i * 7;
    int sr = wi * 7 + i + 3; if (sr >= 56) sr -= 56;
    int sc = wj * 7 + j + 3; if (sc >= 56) sc -= 56;
    const float* xp = x + ((size_t)b * 3136 + sr * 56 + sc) * 192;
    float v0 = xp[lane], v1 = xp[lane + 64], v2 = xp[lane + 128];
    float s = v0 + v1 + v2;
    float q = v0 * v0 + v1 * v1 + v2 * v2;
    for (int off = 32; off > 0; off >>= 1) {
        s += __shfl_down(s, off, 64);
        q += __shfl_down(q, off, 64);
    }
    s = __shfl(s, 0, 64); q = __shfl(q, 0, 64);
    float mean = s * (1.0f / 192.0f);
    float var  = q * (1.0f / 192.0f) - mean * mean;
    float rstd = rsqrtf(var + 1e-5f);
    __hip_bfloat16* op = xw + (size_t)t * 192;
    op[lane]       = __float2bfloat16((v0 - mean) * rstd * g[lane]       + bia[lane]);
    op[lane + 64]  = __float2bfloat16((v1 - mean) * rstd * g[lane + 64]  + bia[lane + 64]);
    op[lane + 128] = __float2bfloat16((v2 - mean) * rstd * g[lane + 128] + bia[lane + 128]);
}

// ---------------- GEMM v2: 128x64 tile, global_load_lds staging ----------------
// C[M][NOUT] = A[M][K] * Bt[NOUT][K]^T + epilogue
// MODE 0: qkv (+bias, scale first 192 cols, out bf16)
// MODE 2: fc1 (+bias, exact gelu, out bf16)
// MODE 3: fc2 (+bias +resid fp32 in-place, out fp32)
template<int MODE, int K, int NOUT>
__global__ __launch_bounds__(256)
void gemm2_k(const __hip_bfloat16* __restrict__ A,
             const __hip_bfloat16* __restrict__ Bt,
             const float* __restrict__ bias,
             const float* __restrict__ resid,
             void* __restrict__ outv)
{
    __shared__ __align__(16) __hip_bfloat16 As[128 * 32];   // 8 KB
    __shared__ __align__(16) __hip_bfloat16 Bs[64 * 32];    // 4 KB
    const int tid  = threadIdx.x;
    const int lane = tid & 63, wave = tid >> 6;
    const int quad = lane >> 4, l15 = lane & 15;
    const int m0 = blockIdx.x * 128, n0 = blockIdx.y * 64;

    // staging addresses: each wave covers 16-row chunks; lane -> (row = c*16 + lane/4, col8 = (lane&3)*8)
    const int arow = lane >> 2, acol = (lane & 3) * 8;
    const __hip_bfloat16* Ag0 = A  + (size_t)(m0 + wave * 32 + arow)      * K + acol;
    const __hip_bfloat16* Ag1 = A  + (size_t)(m0 + wave * 32 + 16 + arow) * K + acol;
    const __hip_bfloat16* Bg  = Bt + (size_t)(n0 + wave * 16 + arow)      * K + acol;
    __hip_bfloat16* Al0 = &As[(wave * 32)      * 32];
    __hip_bfloat16* Al1 = &As[(wave * 32 + 16) * 32];
    __hip_bfloat16* Bl  = &Bs[(wave * 16)      * 32];

    fx4 acc[2][4];
#pragma unroll
    for (int mi = 0; mi < 2; mi++)
#pragma unroll
        for (int ni = 0; ni < 4; ni++) acc[mi][ni] = {0.f, 0.f, 0.f, 0.f};

    for (int k0 = 0; k0 < K; k0 += 32) {
        gload16(Ag0 + k0, Al0);
        gload16(Ag1 + k0, Al1);
        gload16(Bg  + k0, Bl);
        __syncthreads();
        bh8 a0 = *(const bh8*)&As[(wave * 32 + l15)      * 32 + quad * 8];
        bh8 a1 = *(const bh8*)&As[(wave * 32 + 16 + l15) * 32 + quad * 8];
        bh8 b0 = *(const bh8*)&Bs[(0 * 16 + l15) * 32 + quad * 8];
        bh8 b1 = *(const bh8*)&Bs[(1 * 16 + l15) * 32 + quad * 8];
        bh8 b2 = *(const bh8*)&Bs[(2 * 16 + l15) * 32 + quad * 8];
        bh8 b3 = *(const bh8*)&Bs[(3 * 16 + l15) * 32 + quad * 8];
        acc[0][0] = mfma_bf16(a0, b0, acc[0][0]);
        acc[0][1] = mfma_bf16(a0, b1, acc[0][1]);
        acc[0][2] = mfma_bf16(a0, b2, acc[0][2]);
        acc[0][3] = mfma_bf16(a0, b3, acc[0][3]);
        acc[1][0] = mfma_bf16(a1, b0, acc[1][0]);
        acc[1][1] = mfma_bf16(a1, b1, acc[1][1]);
        acc[1][2] = mfma_bf16(a1, b2, acc[1][2]);
        acc[1][3] = mfma_bf16(a1, b3, acc[1][3]);
        __syncthreads();
    }

#pragma unroll
    for (int mi = 0; mi < 2; mi++)
#pragma unroll
    for (int ni = 0; ni < 4; ni++) {
        const int n = n0 + ni * 16 + l15;
        const float bn = bias[n];
#pragma unroll
        for (int r = 0; r < 4; r++) {
            const int m = m0 + wave * 32 + mi * 16 + quad * 4 + r;
            float v = acc[mi][ni][r] + bn;
            if (MODE == 0) {
                if (n < 192) v *= 0.17677669529663687f;   // SCALE = 32^-0.5 on q
                ((__hip_bfloat16*)outv)[(size_t)m * NOUT + n] = __float2bfloat16(v);
            } else if (MODE == 2) {
                v = 0.5f * v * (1.0f + erff(v * 0.70710678118654752f));
                ((__hip_bfloat16*)outv)[(size_t)m * NOUT + n] = __float2bfloat16(v);
            } else {
                ((float*)outv)[(size_t)m * NOUT + n] = v + resid[(size_t)m * NOUT + n];
            }
        }
    }
}

// ---------------- proj + residual + LN2 fused: tile 64 x 192 (full row) ----------------
// x1out = A*Wt + pb + xresid (fp32, -> d_out); y2out = LN(x1out)*g2+b2 (bf16)
__global__ __launch_bounds__(256)
void projln_k(const __hip_bfloat16* __restrict__ A,
              const __hip_bfloat16* __restrict__ Bt,
              const float* __restrict__ pb,
              const float* __restrict__ xresid,
              const float* __restrict__ g2,
              const float* __restrict__ b2,
              float* __restrict__ x1out,
              __hip_bfloat16* __restrict__ y2out)
{
    __shared__ __align__(16) __hip_bfloat16 As[64 * 32];    // 4 KB
    __shared__ __align__(16) __hip_bfloat16 Bs[192 * 32];   // 12 KB
    const int tid  = threadIdx.x;
    const int lane = tid & 63, wave = tid >> 6;
    const int quad = lane >> 4, l15 = lane & 15;
    const int m0 = blockIdx.x * 64;

    const int arow = lane >> 2, acol = (lane & 3) * 8;
    const __hip_bfloat16* Ag = A + (size_t)(m0 + wave * 16 + arow) * 192 + acol;
    __hip_bfloat16* Al = &As[(wave * 16) * 32];
    const __hip_bfloat16* Bg0 = Bt + (size_t)((wave + 0) * 16 + arow) * 192 + acol;
    const __hip_bfloat16* Bg1 = Bt + (size_t)((wave + 4) * 16 + arow) * 192 + acol;
    const __hip_bfloat16* Bg2 = Bt + (size_t)((wave + 8) * 16 + arow) * 192 + acol;
    __hip_bfloat16* Bl0 = &Bs[((wave + 0) * 16) * 32];
    __hip_bfloat16* Bl1 = &Bs[((wave + 4) * 16) * 32];
    __hip_bfloat16* Bl2 = &Bs[((wave + 8) * 16) * 32];

    fx4 acc[12];
#pragma unroll
    for (int ct = 0; ct < 12; ct++) acc[ct] = {0.f, 0.f, 0.f, 0.f};

    for (int k0 = 0; k0 < 192; k0 += 32) {
        gload16(Ag  + k0, Al);
        gload16(Bg0 + k0, Bl0);
        gload16(Bg1 + k0, Bl1);
        gload16(Bg2 + k0, Bl2);
        __syncthreads();
        bh8 a = *(const bh8*)&As[(wave * 16 + l15) * 32 + quad * 8];
#pragma unroll
        for (int ct = 0; ct < 12; ct++) {
            bh8 b = *(const bh8*)&Bs[(ct * 16 + l15) * 32 + quad * 8];
            acc[ct] = mfma_bf16(a, b, acc[ct]);
        }
        __syncthreads();
    }

#pragma unroll
    for (int r = 0; r < 4; r++) {
        const int row = m0 + wave * 16 + quad * 4 + r;
        float vv[12];
        float s = 0.f, q = 0.f;
#pragma unroll
        for (int ct = 0; ct < 12; ct++) {
            const int col = ct * 16 + l15;
            float v = acc[ct][r] + pb[col] + xresid[(size_t)row * 192 + col];
            vv[ct] = v;
            x1out[(size_t)row * 192 + col] = v;
            s += v;
            q += v * v;
        }
        s += __shfl_xor(s, 1, 64);  q += __shfl_xor(q, 1, 64);
        s += __shfl_xor(s, 2, 64);  q += __shfl_xor(q, 2, 64);
        s += __shfl_xor(s, 4, 64);  q += __shfl_xor(q, 4, 64);
        s += __shfl_xor(s, 8, 64);  q += __shfl_xor(q, 8, 64);
        float mean = s * (1.0f / 192.0f);
        float var  = q * (1.0f / 192.0f) - mean * mean;
        float rstd = rsqrtf(var + 1e-5f);
#pragma unroll
        for (int ct = 0; ct < 12; ct++) {
            const int col = ct * 16 + l15;
            float y = (vv[ct] - mean) * rstd * g2[col] + b2[col];
            y2out[(size_t)row * 192 + col] = __float2bfloat16(y);
        }
    }
}

// ---------------- attention: one block per (window, head) ----------------
__global__ __launch_bounds__(256)
void attn_k(const __hip_bfloat16* __restrict__ qkv,   // [2048][49][576]
            const float* __restrict__ bias_table,
            __hip_bfloat16* __restrict__ aout)        // orig token order
{
    __shared__ __align__(16) __hip_bfloat16 Qb[64 * 32];
    __shared__ __align__(16) __hip_bfloat16 Kb[64 * 32];
    __shared__ __align__(16) __hip_bfloat16 Vt[32 * 64];   // Vt[d][m]
    __shared__ __align__(16) __hip_bfloat16 Ps[64 * 72];   // padded stride 72
    __shared__ float bias_h[169];

    const int tid  = threadIdx.x;
    const int lane = tid & 63, wave = tid >> 6;
    const int quad = lane >> 4, l15 = lane & 15;
    const int w = blockIdx.x / 6, hd = blockIdx.x % 6;
    const int b = w >> 6, wrem = w & 63, wi = wrem >> 3, wj = wrem & 7;
    const size_t base = (size_t)w * 49 * 576 + hd * 32;

    if (tid < 169) bias_h[tid] = bias_table[tid * 6 + hd];

    bh8 z = {0, 0, 0, 0, 0, 0, 0, 0};
    {
        int row = tid >> 2, ch = (tid & 3) * 8;
        if (row < 49) {
            *(bh8*)&Qb[row * 32 + ch] = *(const bh8*)(qkv + base + (size_t)row * 576 + ch);
            *(bh8*)&Kb[row * 32 + ch] = *(const bh8*)(qkv + base + (size_t)row * 576 + 192 + ch);
        } else {
            *(bh8*)&Qb[row * 32 + ch] = z;
            *(bh8*)&Kb[row * 32 + ch] = z;
        }
        *(bh8*)&Vt[tid * 8] = z;    // zero all of Vt
    }
    __syncthreads();
    for (int idx = tid; idx < 49 * 32; idx += 256) {       // V transpose scatter
        int n = idx >> 5, d = idx & 31;
        Vt[d * 64 + n] = qkv[base + (size_t)n * 576 + 384 + d];
    }
    __syncthreads();

    // ---- scores S = Q K^T ----
    fx4 zf = {0.f, 0.f, 0.f, 0.f};
    bh8 aq = *(const bh8*)&Qb[(wave * 16 + l15) * 32 + quad * 8];
    fx4 sarr[4];
#pragma unroll
    for (int ni = 0; ni < 4; ni++) {
        bh8 bk = *(const bh8*)&Kb[(ni * 16 + l15) * 32 + quad * 8];
        sarr[ni] = mfma_bf16(aq, bk, zf);
    }

    // ---- bias + mask + softmax ----
    int iarr[4], ria[4], cia[4], mbi[4];
#pragma unroll
    for (int r = 0; r < 4; r++) {
        int i = wave * 16 + quad * 4 + r;
        int ri = i / 7, ci = i - ri * 7;
        iarr[r] = i; ria[r] = ri; cia[r] = ci;
        int ar = wi * 7 + ri, ac = wj * 7 + ci;
        int br = (ar < 49) ? 0 : ((ar < 53) ? 1 : 2);
        int bc = (ac < 49) ? 0 : ((ac < 53) ? 1 : 2);
        mbi[r] = br * 3 + bc;
    }
    float vals[4][4];   // [ni][r]
#pragma unroll
    for (int ni = 0; ni < 4; ni++) {
        int jcol = ni * 16 + l15;
        int rj = jcol / 7, cj = jcol - rj * 7;
        int ar = wi * 7 + rj, ac = wj * 7 + cj;
        int br = (ar < 49) ? 0 : ((ar < 53) ? 1 : 2);
        int bc = (ac < 49) ? 0 : ((ac < 53) ? 1 : 2);
        int mbj = br * 3 + bc;
#pragma unroll
        for (int r = 0; r < 4; r++) {
            float v;
            if (jcol >= 49)            v = -1e30f;
            else if (iarr[r] >= 49)    v = 0.0f;
            else {
                int bidx = (ria[r] - rj + 6) * 13 + (cia[r] - cj + 6);
                v = sarr[ni][r] + bias_h[bidx] + ((mbi[r] != mbj) ? -100.0f : 0.0f);
            }
            vals[ni][r] = v;
        }
    }
#pragma unroll
    for (int r = 0; r < 4; r++) {
        float mx = fmaxf(fmaxf(vals[0][r], vals[1][r]), fmaxf(vals[2][r], vals[3][r]));
        mx = fmaxf(mx, __shfl_xor(mx, 1, 64));
        mx = fmaxf(mx, __shfl_xor(mx, 2, 64));
        mx = fmaxf(mx, __shfl_xor(mx, 4, 64));
        mx = fmaxf(mx, __shfl_xor(mx, 8, 64));
        float e0 = __expf(vals[0][r] - mx);
        float e1 = __expf(vals[1][r] - mx);
        float e2 = __expf(vals[2][r] - mx);
        float e3 = __expf(vals[3][r] - mx);
        float sm = e0 + e1 + e2 + e3;
        sm += __shfl_xor(sm, 1, 64);
        sm += __shfl_xor(sm, 2, 64);
        sm += __shfl_xor(sm, 4, 64);
        sm += __shfl_xor(sm, 8, 64);
        float inv = 1.0f / sm;
        int prow = (wave * 16 + quad * 4 + r) * 72;
        Ps[prow + 0 * 16 + l15] = __float2bfloat16(e0 * inv);
        Ps[prow + 1 * 16 + l15] = __float2bfloat16(e1 * inv);
        Ps[prow + 2 * 16 + l15] = __float2bfloat16(e2 * inv);
        Ps[prow + 3 * 16 + l15] = __float2bfloat16(e3 * inv);
    }
    __syncthreads();

    // ---- O = P V ----
    fx4 o0 = zf, o1 = zf;
#pragma unroll
    for (int k0 = 0; k0 < 64; k0 += 32) {
        bh8 ap  = *(const bh8*)&Ps[(wave * 16 + l15) * 72 + k0 + quad * 8];
        bh8 bv0 = *(const bh8*)&Vt[(l15)      * 64 + k0 + quad * 8];
        bh8 bv1 = *(const bh8*)&Vt[(16 + l15) * 64 + k0 + quad * 8];
        o0 = mfma_bf16(ap, bv0, o0);
        o1 = mfma_bf16(ap, bv1, o1);
    }

    // ---- write out in ORIGINAL token order ----
#pragma unroll
    for (int r = 0; r < 4; r++) {
        int m = wave * 16 + quad * 4 + r;
        if (m < 49) {
            int i = m / 7, j2 = m - i * 7;
            int orow = wi * 7 + i + 3;  if (orow >= 56) orow -= 56;
            int ocol = wj * 7 + j2 + 3; if (ocol >= 56) ocol -= 56;
            size_t t = (size_t)b * 3136 + orow * 56 + ocol;
            aout[t * 192 + hd * 32 + l15]      = __float2bfloat16(o0[r]);
            aout[t * 192 + hd * 32 + 16 + l15] = __float2bfloat16(o1[r]);
        }
    }
}

// ---------------- launch ----------------
// ws_size ~= 308,281,344 B (measured from harness poison-fill WRITE_SIZE).
// Layout (peak 193.6 MB):
//   buf1 @ 0          38,535,168 B : xw (window order) -> attn_out (orig order) -> y2
//   buf2 @ 38,535,168 154,140,672 B: qkv full (115.6 MB) then hbuf full (154.1 MB)
//   weights @ 192,675,840 .. 193,560,576
//   x1 lives in d_out (fp32); fc2 does in-place owner-computes residual add on d_out.
extern "C" void kernel_launch(void* const* d_in, const int* in_sizes, int n_in,
                              void* d_out, int out_size, void* d_ws, size_t ws_size,
                              hipStream_t stream)
{
    const float* x      = (const float*)d_in[0];
    const float* n1g    = (const float*)d_in[1];
    const float* n1b    = (const float*)d_in[2];
    const float* qkv_w  = (const float*)d_in[3];
    const float* qkv_b  = (const float*)d_in[4];
    const float* proj_w = (const float*)d_in[5];
    const float* proj_b = (const float*)d_in[6];
    const float* btab   = (const float*)d_in[7];
    const float* n2g    = (const float*)d_in[8];
    const float* n2b    = (const float*)d_in[9];
    const float* fc1_w  = (const float*)d_in[10];
    const float* fc1_b  = (const float*)d_in[11];
    const float* fc2_w  = (const float*)d_in[12];
    const float* fc2_b  = (const float*)d_in[13];

    char* ws = (char*)d_ws;
    __hip_bfloat16* buf1    = (__hip_bfloat16*)(ws + 0);           // 38,535,168 B
    __hip_bfloat16* buf2    = (__hip_bfloat16*)(ws + 38535168);    // 154,140,672 B
    __hip_bfloat16* wt_qkv  = (__hip_bfloat16*)(ws + 192675840);   // 221,184 B
    __hip_bfloat16* wt_proj = (__hip_bfloat16*)(ws + 192897024);   // 73,728 B
    __hip_bfloat16* wt_fc1  = (__hip_bfloat16*)(ws + 192970752);   // 294,912 B
    __hip_bfloat16* wt_fc2  = (__hip_bfloat16*)(ws + 193265664);   // 294,912 B
    float*          x1      = (float*)d_out;                       // 77,070,336 B

    convw_k<<<dim3(432), 256, 0, stream>>>(qkv_w, wt_qkv, 192, 576);
    convw_k<<<dim3(144), 256, 0, stream>>>(proj_w, wt_proj, 192, 192);
    convw_k<<<dim3(576), 256, 0, stream>>>(fc1_w, wt_fc1, 192, 768);
    convw_k<<<dim3(576), 256, 0, stream>>>(fc2_w, wt_fc2, 768, 192);

    // LN1 + shift + window partition: 100352 tokens -> buf1 (bf16, window order)
    ln1_gather_k<<<dim3(25088), 256, 0, stream>>>(x, n1g, n1b, buf1);

    // QKV: [100352 x 192] x [576 x 192]^T -> buf2 (bf16)
    gemm2_k<0, 192, 576><<<dim3(784, 9), 256, 0, stream>>>(buf1, wt_qkv, qkv_b, nullptr, buf2);

    // attention: 2048 windows x 6 heads -> buf1 (bf16, orig token order)
    attn_k<<<dim3(12288), 256, 0, stream>>>(buf2, btab, buf1);

    // proj + residual + LN2: x1 -> d_out (fp32), y2 -> buf1 (bf16, in-place over attn_out)
    projln_k<<<dim3(1568), 256, 0, stream>>>(buf1, wt_proj, proj_b, x, n2g, n2b, x1, buf1);

    // FC1 + gelu: -> buf2 (bf16, 154 MB)
    gemm2_k<2, 192, 768><<<dim3(784, 12), 256, 0, stream>>>(buf1, wt_fc1, fc1_b, nullptr, buf2);

    // FC2 + residual (in-place on d_out)
    gemm2_k<3, 768, 192><<<dim3(784, 3), 256, 0, stream>>>(buf2, wt_fc2, fc2_b, x1, x1);
}